// Round 6
// baseline (1610.283 us; speedup 1.0000x reference)
//
#include <hip/hip_runtime.h>
#include <hip/hip_bf16.h>

using bf16 = __hip_bfloat16;

#define HH 32
#define HH2 64
#define NRBF_ 20
#define NL 5
#define NNN 256
#define KBW 8
#define PGN 4024
#define TTAB 2048
#define NBKT 1006           // NNODE / 128 exactly
constexpr int NNODE = 128768;
constexpr int NEDGE = 2060288;
constexpr float BNEPS = 1e-5f;
constexpr float PI_F = 3.14159265358979323846f;

// ---------------- node RBF embed -> f32 h
__global__ void __launch_bounds__(256) k_node_embed(const float* __restrict__ x3d,
                                                    const float* __restrict__ wlen,
                                                    const float* __restrict__ blen,
                                                    float* __restrict__ hbuf) {
  __shared__ float wl[NRBF_ * HH];
  __shared__ float bl[HH];
  int t = threadIdx.x;
  for (int j = t; j < NRBF_ * HH; j += 256) wl[j] = wlen[j];
  if (t < HH) bl[t] = blen[t];
  __syncthreads();
  int idx = blockIdx.x * 256 + t;
  int n = idx >> 5, c = idx & 31;
  float x = x3d[n];
  float acc = bl[c];
#pragma unroll
  for (int k = 0; k < NRBF_; ++k) {
    float d = x - 0.1f * (float)k;
    acc = fmaf(__expf(-10.f * d * d), wl[k * HH + c], acc);
  }
  hbuf[idx] = acc;
}

// ---------------- build ea lerp table
__global__ void __launch_bounds__(256) k_tab(const float* __restrict__ wang,
                                             const float* __restrict__ bang,
                                             float* __restrict__ tab) {
  __shared__ float wa[NRBF_ * HH];
  __shared__ float ba[HH];
  int t = threadIdx.x;
  for (int j = t; j < NRBF_ * HH; j += 256) wa[j] = wang[j];
  if (t < HH) ba[t] = bang[t];
  __syncthreads();
  int idx = blockIdx.x * 256 + t;
  int row = idx >> 5, c = idx & 31;
  float ang = (float)row * (PI_F / (float)(TTAB - 1));
  const float step = PI_F / 19.f;
  float acc = ba[c];
#pragma unroll
  for (int k = 0; k < NRBF_; ++k) {
    float d = ang - step * (float)k;
    acc = fmaf(__expf(-10.f * d * d), wa[k * HH + c], acc);
  }
  tab[row * HH + c] = acc;
}

// ---------------- histogram of dst
__global__ void __launch_bounds__(256) k_hist(const int* __restrict__ dst, int* __restrict__ counts) {
  int e = blockIdx.x * 256 + threadIdx.x;
  atomicAdd(&counts[dst[e]], 1);
}

// ---------------- scan step 1
__global__ void __launch_bounds__(256) k_scan1(const int* __restrict__ counts, int* __restrict__ bsum) {
  __shared__ int sd[256];
  int t = threadIdx.x;
  sd[t] = counts[blockIdx.x * 256 + t];
  __syncthreads();
  for (int s = 128; s > 0; s >>= 1) { if (t < s) sd[t] += sd[t + s]; __syncthreads(); }
  if (t == 0) bsum[blockIdx.x] = sd[0];
}

// ---------------- scan step 2
__global__ void __launch_bounds__(512) k_scan2(const int* __restrict__ bsum, int* __restrict__ boff) {
  __shared__ int sd[512];
  int t = threadIdx.x;
  int v = (t < 503) ? bsum[t] : 0;
  sd[t] = v;
  __syncthreads();
  for (int off = 1; off < 512; off <<= 1) {
    int x = (t >= off) ? sd[t - off] : 0;
    __syncthreads();
    sd[t] += x;
    __syncthreads();
  }
  if (t < 503) boff[t] = sd[t] - v;
}

// ---------------- scan step 3: rowptr + per-node cursor (= rowptr copy)
__global__ void __launch_bounds__(256) k_scan3(const int* __restrict__ counts, const int* __restrict__ boff,
                                               int* __restrict__ rowptr, int* __restrict__ cursor) {
  __shared__ int sd[256];
  int t = threadIdx.x;
  int i = blockIdx.x * 256 + t;
  int v = counts[i];
  sd[t] = v;
  __syncthreads();
  for (int off = 1; off < 256; off <<= 1) {
    int x = (t >= off) ? sd[t - off] : 0;
    __syncthreads();
    sd[t] += x;
    __syncthreads();
  }
  int excl = sd[t] - v + boff[blockIdx.x];
  rowptr[i] = excl;
  cursor[i] = excl;
  if (i == NNODE - 1) rowptr[NNODE] = excl + v;
}

// ---------------- bucket cursor init: bcur[b] = rowptr[b<<7]
__global__ void __launch_bounds__(256) k_bcinit(const int* __restrict__ rowptr, int* __restrict__ bcur) {
  int b = blockIdx.x * 256 + threadIdx.x;
  if (b < NBKT) bcur[b] = rowptr[b << 7];
}

// ---------------- pass A: coarse bucket append (frontier-coalesced writes)
__global__ void __launch_bounds__(256) k_binA(const int* __restrict__ srcA,
                                              const int* __restrict__ dstA,
                                              const float* __restrict__ eattr,
                                              int* __restrict__ bcur,
                                              int2* __restrict__ pkA) {
  int e = blockIdx.x * 256 + threadIdx.x;
  int d = dstA[e];
  int b = d >> 7;
  int pos = atomicAdd(&bcur[b], 1);
  pkA[pos] = make_int2(srcA[e] | ((d & 127) << 17), __float_as_int(eattr[e]));
}

// ---------------- pass B: fine sort within bucket (16KB region, L2-resident scatter)
__global__ void __launch_bounds__(256) k_binB(const int* __restrict__ rowptr,
                                              const int2* __restrict__ pkA,
                                              int* __restrict__ cursor,
                                              int2* __restrict__ pk) {
  int b = blockIdx.x;
  int b0 = b << 7;
  int base = rowptr[b0];
  int nend = (b0 + 128 < NNODE) ? b0 + 128 : NNODE;
  int end = rowptr[nend];
  for (int i = base + threadIdx.x; i < end; i += 256) {
    int2 q = pkA[i];
    int d = b0 + ((unsigned)q.x >> 17);
    int pos = atomicAdd(&cursor[d], 1);
    pk[pos] = make_int2(q.x & 0x1FFFF, q.y);
  }
}

// ---------------- init identity affine
__global__ void k_affinit(float* __restrict__ affH) {
  int o = threadIdx.x;
  if (o < HH) { affH[o] = 1.f; affH[HH + o] = 0.f; }
}

// ---------------- layer kernel A: grid-stride aggregate + t@w1+b1, register BN1 stats
__global__ void __launch_bounds__(256) k_layerA(const float* __restrict__ hbuf,
                                                const int* __restrict__ rowptr,
                                                const int2* __restrict__ pk,
                                                const float* __restrict__ tab,
                                                const float* __restrict__ affH,
                                                const float* __restrict__ w1g,
                                                const float* __restrict__ b1g,
                                                const float* __restrict__ epsg,
                                                float* __restrict__ y1buf,
                                                float* __restrict__ statsA,
                                                int l, int relu) {
  __shared__ float w1s[HH * HH2];
  __shared__ float b1s[HH2];
  __shared__ float tb[8][HH + 1];
  __shared__ float ps[HH2], pq[HH2];
  int t = threadIdx.x;
  const float* w1l = w1g + l * HH * HH2;
  for (int j = t; j < HH * HH2; j += 256) w1s[j] = w1l[j];
  if (t < HH2) { b1s[t] = b1g[l * HH2 + t]; ps[t] = 0.f; pq[t] = 0.f; }
  int g = t >> 5, c = t & 31;
  float sc = affH[c], sh = affH[HH + c];
  float epsv = 1.f + epsg[l];
  float lo = relu ? 0.f : -3.4e38f;
  const float angsc = (float)(TTAB - 1) / PI_F;
  float s0a = 0.f, s0q = 0.f, s1a = 0.f, s1q = 0.f;
  __syncthreads();
  int stride = gridDim.x * 8;
  int iters = (NNODE + stride - 1) / stride;
  int n = blockIdx.x * 8 + g;
  for (int it = 0; it < iters; ++it, n += stride) {
    bool val = n < NNODE;
    float tv = 0.f;
    if (val) {
      int p0 = rowptr[n], p1 = rowptr[n + 1];
      float hn = fmaxf(fmaf(hbuf[n * HH + c], sc, sh), lo);
      float acc = 0.f;
      int p = p0;
      for (; p + 4 <= p1; p += 4) {
        int2 q0 = pk[p], q1 = pk[p + 1], q2 = pk[p + 2], q3 = pk[p + 3];
        float h0 = hbuf[q0.x * HH + c];
        float h1 = hbuf[q1.x * HH + c];
        float h2 = hbuf[q2.x * HH + c];
        float h3 = hbuf[q3.x * HH + c];
        float u0 = __int_as_float(q0.y) * angsc; int i0 = min((int)u0, TTAB - 2); float f0 = u0 - (float)i0;
        float u1 = __int_as_float(q1.y) * angsc; int i1 = min((int)u1, TTAB - 2); float f1 = u1 - (float)i1;
        float u2 = __int_as_float(q2.y) * angsc; int i2 = min((int)u2, TTAB - 2); float f2 = u2 - (float)i2;
        float u3 = __int_as_float(q3.y) * angsc; int i3 = min((int)u3, TTAB - 2); float f3 = u3 - (float)i3;
        float t00 = tab[i0 * HH + c], t01 = tab[i0 * HH + HH + c];
        float t10 = tab[i1 * HH + c], t11 = tab[i1 * HH + HH + c];
        float t20 = tab[i2 * HH + c], t21 = tab[i2 * HH + HH + c];
        float t30 = tab[i3 * HH + c], t31 = tab[i3 * HH + HH + c];
        float e0 = fmaf(f0, t01 - t00, t00);
        float e1 = fmaf(f1, t11 - t10, t10);
        float e2 = fmaf(f2, t21 - t20, t20);
        float e3 = fmaf(f3, t31 - t30, t30);
        h0 = fmaxf(fmaf(h0, sc, sh), lo);
        h1 = fmaxf(fmaf(h1, sc, sh), lo);
        h2 = fmaxf(fmaf(h2, sc, sh), lo);
        h3 = fmaxf(fmaf(h3, sc, sh), lo);
        acc += fmaxf(h0 + e0, 0.f) + fmaxf(h1 + e1, 0.f) + fmaxf(h2 + e2, 0.f) + fmaxf(h3 + e3, 0.f);
      }
      for (; p < p1; ++p) {
        int2 q0 = pk[p];
        float h0 = fmaxf(fmaf(hbuf[q0.x * HH + c], sc, sh), lo);
        float u0 = __int_as_float(q0.y) * angsc; int i0 = min((int)u0, TTAB - 2); float f0 = u0 - (float)i0;
        float t00 = tab[i0 * HH + c], t01 = tab[i0 * HH + HH + c];
        acc += fmaxf(h0 + fmaf(f0, t01 - t00, t00), 0.f);
      }
      tv = fmaf(epsv, hn, acc);
    }
    tb[g][c] = tv;                      // intra-group (intra-wave) exchange: no block barrier needed
    __builtin_amdgcn_wave_barrier();
    if (val) {
      float y0 = b1s[c], y1 = b1s[HH + c];
#pragma unroll
      for (int k = 0; k < HH; ++k) {
        float tk = tb[g][k];
        y0 = fmaf(tk, w1s[k * HH2 + c], y0);
        y1 = fmaf(tk, w1s[k * HH2 + HH + c], y1);
      }
      y1buf[n * HH2 + c] = y0;
      y1buf[n * HH2 + HH + c] = y1;
      s0a += y0; s0q += y0 * y0; s1a += y1; s1q += y1 * y1;
    }
    __builtin_amdgcn_wave_barrier();
  }
  s0a += __shfl_xor(s0a, 32); s0q += __shfl_xor(s0q, 32);
  s1a += __shfl_xor(s1a, 32); s1q += __shfl_xor(s1q, 32);
  if ((t & 32) == 0) {
    atomicAdd(&ps[c], s0a); atomicAdd(&pq[c], s0q);
    atomicAdd(&ps[HH + c], s1a); atomicAdd(&pq[HH + c], s1q);
  }
  __syncthreads();
  if (t < HH2) {
    atomicAdd(&statsA[l * 128 + t], ps[t]);
    atomicAdd(&statsA[l * 128 + 64 + t], pq[t]);
  }
}

// ---------------- BN1 solve (64 ch)
__global__ void k_bn1(const float* __restrict__ statsA, const float* __restrict__ g1,
                      const float* __restrict__ bb1, float* __restrict__ aff1, int l) {
  int o = threadIdx.x;
  float sum = statsA[l * 128 + o], sq = statsA[l * 128 + 64 + o];
  float mean = sum / (float)NNODE;
  float var = fmaxf(sq / (float)NNODE - mean * mean, 0.f);
  float s = g1[l * HH2 + o] * rsqrtf(var + BNEPS);
  aff1[o] = s;
  aff1[HH2 + o] = bb1[l * HH2 + o] - mean * s;
}

// ---------------- layer kernel C: grid-stride, BN1 affine->relu->@w2+b2, register BN2 stats
__global__ void __launch_bounds__(256) k_layerC(const float* __restrict__ y1buf,
                                                const float* __restrict__ aff1,
                                                const float* __restrict__ w2g,
                                                const float* __restrict__ b2g,
                                                float* __restrict__ hbuf,
                                                float* __restrict__ statsC, int l) {
  __shared__ float w2s[HH2 * HH];
  __shared__ float b2s[HH];
  __shared__ float ab[8][HH2 + 1];
  __shared__ float ps[HH], pq[HH];
  int t = threadIdx.x;
  const float* w2l = w2g + l * HH2 * HH;
  for (int j = t; j < HH2 * HH; j += 256) w2s[j] = w2l[j];
  if (t < HH) { b2s[t] = b2g[l * HH + t]; ps[t] = 0.f; pq[t] = 0.f; }
  int g = t >> 5, c = t & 31;
  float sa = 0.f, sq = 0.f;
  __syncthreads();
  int stride = gridDim.x * 8;
  int iters = (NNODE + stride - 1) / stride;
  int n = blockIdx.x * 8 + g;
  for (int it = 0; it < iters; ++it, n += stride) {
    bool val = n < NNODE;
    float a0 = 0.f, a1 = 0.f;
    if (val) {
      a0 = fmaf(y1buf[n * HH2 + c], aff1[c], aff1[HH2 + c]);
      a1 = fmaf(y1buf[n * HH2 + HH + c], aff1[HH + c], aff1[HH2 + HH + c]);
    }
    ab[g][c] = fmaxf(a0, 0.f);
    ab[g][HH + c] = fmaxf(a1, 0.f);
    __builtin_amdgcn_wave_barrier();
    if (val) {
      float z = b2s[c];
#pragma unroll
      for (int k = 0; k < HH2; ++k) z = fmaf(ab[g][k], w2s[k * HH + c], z);
      hbuf[n * HH + c] = z;
      sa += z; sq += z * z;
    }
    __builtin_amdgcn_wave_barrier();
  }
  sa += __shfl_xor(sa, 32); sq += __shfl_xor(sq, 32);
  if ((t & 32) == 0) { atomicAdd(&ps[c], sa); atomicAdd(&pq[c], sq); }
  __syncthreads();
  if (t < HH) {
    atomicAdd(&statsC[l * 64 + t], sa = ps[t]);
    atomicAdd(&statsC[l * 64 + 32 + t], pq[t]);
  }
}

// ---------------- BN2 solve
__global__ void k_bn2(const float* __restrict__ statsC, const float* __restrict__ gg,
                      const float* __restrict__ bb, float* __restrict__ affH, int l) {
  int o = threadIdx.x;
  float sum = statsC[l * 64 + o], sq = statsC[l * 64 + 32 + o];
  float mean = sum / (float)NNODE;
  float var = fmaxf(sq / (float)NNODE - mean * mean, 0.f);
  float s = gg[l * HH + o] * rsqrtf(var + BNEPS);
  affH[o] = s;
  affH[HH + o] = bb[l * HH + o] - mean * s;
}

// ---------------- output: band-only writes (d_out pre-zeroed by memset)
__global__ void __launch_bounds__(256) k_output(const float* __restrict__ hbuf,
                                                const float* __restrict__ affH,
                                                const float* __restrict__ lng,
                                                const float* __restrict__ lnb,
                                                float* __restrict__ out) {
  __shared__ float nrb[16 * 33];
  int t = threadIdx.x;
  int gi = blockIdx.x;
  int g = gi >> 8, i = gi & 255;
  int jlo = (i - KBW > 0) ? i - KBW : 0;
  int jhi = (i + KBW < NNN - 1) ? i + KBW : NNN - 1;
  int cnt = jhi - jlo;  // valid count (excludes diagonal)
  int Ai = (i <= 8) ? i * (i - 1) / 2 : 28 + 8 * (i - 8);
  int Bi = (i <= 248) ? 8 * i : 2012 - (256 - i) * (255 - i) / 2;
  int nb = g * PGN + Ai + Bi;
  int r = t >> 5, c = t & 31;
  float sc = affH[c], sh = affH[HH + c];
  float lg = lng[c], lb = lnb[c];
  for (int rr = r; rr < cnt; rr += 8) {
    float v = fmaf(hbuf[(nb + rr) * HH + c], sc, sh);
    float s = v;
#pragma unroll
    for (int off = 16; off > 0; off >>= 1) s += __shfl_xor(s, off, 32);
    float mean = s * (1.f / 32.f);
    float d = v - mean;
    float q = d * d;
#pragma unroll
    for (int off = 16; off > 0; off >>= 1) q += __shfl_xor(q, off, 32);
    float var = q * (1.f / 32.f);
    nrb[rr * 33 + c] = d * rsqrtf(var + BNEPS) * lg + lb;
  }
  __syncthreads();
  int ch = t >> 3, k0 = t & 7;
  size_t base = (((size_t)g * HH + ch) * NNN + i) * NNN;
  for (int k = k0; k <= cnt; k += 8) {
    int j = jlo + k;
    if (j != i) {
      int rr = k - (j > i ? 1 : 0);
      out[base + j] = nrb[rr * 33 + ch];
    }
  }
}

extern "C" void kernel_launch(void* const* d_in, const int* in_sizes, int n_in,
                              void* d_out, int out_size, void* d_ws, size_t ws_size,
                              hipStream_t stream) {
  (void)in_sizes; (void)n_in;
  const float* x3d   = (const float*)d_in[0];
  const float* eattr = (const float*)d_in[1];
  const int*   eidx  = (const int*)d_in[2];
  const float* wlen = (const float*)d_in[5];
  const float* blen = (const float*)d_in[6];
  const float* wang = (const float*)d_in[7];
  const float* bang = (const float*)d_in[8];
  const float* w1g  = (const float*)d_in[9];
  const float* b1g  = (const float*)d_in[10];
  const float* g1   = (const float*)d_in[11];
  const float* bb1  = (const float*)d_in[12];
  const float* w2g  = (const float*)d_in[13];
  const float* b2g  = (const float*)d_in[14];
  const float* epsg = (const float*)d_in[15];
  const float* bng  = (const float*)d_in[16];
  const float* bnb  = (const float*)d_in[17];
  const float* lng  = (const float*)d_in[18];
  const float* lnb  = (const float*)d_in[19];
  float* out = (float*)d_out;

  char* ws = (char*)d_ws;
  size_t off = 0;
  auto alloc = [&](size_t bytes) {
    void* p = ws + off;
    off += (bytes + 255) & ~(size_t)255;
    return p;
  };
  int2*  pkA        = (int2*)alloc((size_t)NEDGE * 8);
  int2*  pk         = (int2*)alloc((size_t)NEDGE * 8);
  int*   rowptr     = (int*)alloc((size_t)(NNODE + 1) * 4);
  int*   counts     = (int*)alloc((size_t)NNODE * 4);
  int*   cursor     = (int*)alloc((size_t)NNODE * 4);
  float* hbuf       = (float*)alloc((size_t)NNODE * HH * 4);
  float* y1buf      = (float*)alloc((size_t)NNODE * HH2 * 4);
  float* tab        = (float*)alloc((size_t)TTAB * HH * 4);
  float* statsA     = (float*)alloc(NL * 128 * 4);
  float* statsC     = (float*)alloc(NL * 64 * 4);
  float* aff1       = (float*)alloc(128 * 4);
  float* affH       = (float*)alloc(64 * 4);
  int*   bsum       = (int*)alloc(503 * 4);
  int*   boff       = (int*)alloc(503 * 4);
  int*   bcur       = (int*)alloc(NBKT * 4);

  if (off > ws_size) {
    hipMemsetAsync(d_out, 0x7F, (size_t)out_size * 4, stream);
    return;
  }

  hipMemsetAsync(d_out, 0, (size_t)out_size * 4, stream);
  hipMemsetAsync(counts, 0, (size_t)NNODE * 4, stream);
  hipMemsetAsync(statsA, 0, NL * 128 * 4, stream);
  hipMemsetAsync(statsC, 0, NL * 64 * 4, stream);

  k_node_embed<<<NNODE * HH / 256, 256, 0, stream>>>(x3d, wlen, blen, hbuf);
  k_tab<<<TTAB * HH / 256, 256, 0, stream>>>(wang, bang, tab);
  k_hist<<<NEDGE / 256, 256, 0, stream>>>(eidx + NEDGE, counts);
  k_scan1<<<NNODE / 256, 256, 0, stream>>>(counts, bsum);
  k_scan2<<<1, 512, 0, stream>>>(bsum, boff);
  k_scan3<<<NNODE / 256, 256, 0, stream>>>(counts, boff, rowptr, cursor);
  k_bcinit<<<(NBKT + 255) / 256, 256, 0, stream>>>(rowptr, bcur);
  k_binA<<<NEDGE / 256, 256, 0, stream>>>(eidx, eidx + NEDGE, eattr, bcur, pkA);
  k_binB<<<NBKT, 256, 0, stream>>>(rowptr, pkA, cursor, pk);
  k_affinit<<<1, 64, 0, stream>>>(affH);

  for (int l = 0; l < NL; ++l) {
    k_layerA<<<2048, 256, 0, stream>>>(hbuf, rowptr, pk, tab, affH,
                                       w1g, b1g, epsg, y1buf, statsA, l, l >= 1 ? 1 : 0);
    k_bn1<<<1, 64, 0, stream>>>(statsA, g1, bb1, aff1, l);
    k_layerC<<<2048, 256, 0, stream>>>(y1buf, aff1, w2g, b2g, hbuf, statsC, l);
    k_bn2<<<1, 32, 0, stream>>>(statsC, bng, bnb, affH, l);
  }

  k_output<<<NNN * 32, 256, 0, stream>>>(hbuf, affH, lng, lnb, out);
}

// Round 7
// 1233.618 us; speedup vs baseline: 1.3053x; 1.3053x over previous
//
#include <hip/hip_runtime.h>
#include <hip/hip_bf16.h>

using bf16 = __hip_bfloat16;

#define HH 32
#define HH2 64
#define NRBF_ 20
#define NL 5
#define NNN 256
#define KBW 8
#define PGN 4024
#define TTAB 2048
constexpr int NNODE = 128768;
constexpr int NEDGE = 2060288;
constexpr float BNEPS = 1e-5f;
constexpr float PI_F = 3.14159265358979323846f;

// ---------------- node RBF embed -> f32 h
__global__ void __launch_bounds__(256) k_node_embed(const float* __restrict__ x3d,
                                                    const float* __restrict__ wlen,
                                                    const float* __restrict__ blen,
                                                    float* __restrict__ hbuf) {
  __shared__ float wl[NRBF_ * HH];
  __shared__ float bl[HH];
  int t = threadIdx.x;
  for (int j = t; j < NRBF_ * HH; j += 256) wl[j] = wlen[j];
  if (t < HH) bl[t] = blen[t];
  __syncthreads();
  int idx = blockIdx.x * 256 + t;
  int n = idx >> 5, c = idx & 31;
  float x = x3d[n];
  float acc = bl[c];
#pragma unroll
  for (int k = 0; k < NRBF_; ++k) {
    float d = x - 0.1f * (float)k;
    acc = fmaf(__expf(-10.f * d * d), wl[k * HH + c], acc);
  }
  hbuf[idx] = acc;
}

// ---------------- build ea lerp table
__global__ void __launch_bounds__(256) k_tab(const float* __restrict__ wang,
                                             const float* __restrict__ bang,
                                             float* __restrict__ tab) {
  __shared__ float wa[NRBF_ * HH];
  __shared__ float ba[HH];
  int t = threadIdx.x;
  for (int j = t; j < NRBF_ * HH; j += 256) wa[j] = wang[j];
  if (t < HH) ba[t] = bang[t];
  __syncthreads();
  int idx = blockIdx.x * 256 + t;
  int row = idx >> 5, c = idx & 31;
  float ang = (float)row * (PI_F / (float)(TTAB - 1));
  const float step = PI_F / 19.f;
  float acc = ba[c];
#pragma unroll
  for (int k = 0; k < NRBF_; ++k) {
    float d = ang - step * (float)k;
    acc = fmaf(__expf(-10.f * d * d), wa[k * HH + c], acc);
  }
  tab[row * HH + c] = acc;
}

// ---------------- histogram of dst
__global__ void __launch_bounds__(256) k_hist(const int* __restrict__ dst, int* __restrict__ counts) {
  int e = blockIdx.x * 256 + threadIdx.x;
  atomicAdd(&counts[dst[e]], 1);
}

// ---------------- scan step 1
__global__ void __launch_bounds__(256) k_scan1(const int* __restrict__ counts, int* __restrict__ bsum) {
  __shared__ int sd[256];
  int t = threadIdx.x;
  sd[t] = counts[blockIdx.x * 256 + t];
  __syncthreads();
  for (int s = 128; s > 0; s >>= 1) { if (t < s) sd[t] += sd[t + s]; __syncthreads(); }
  if (t == 0) bsum[blockIdx.x] = sd[0];
}

// ---------------- scan step 2
__global__ void __launch_bounds__(512) k_scan2(const int* __restrict__ bsum, int* __restrict__ boff) {
  __shared__ int sd[512];
  int t = threadIdx.x;
  int v = (t < 503) ? bsum[t] : 0;
  sd[t] = v;
  __syncthreads();
  for (int off = 1; off < 512; off <<= 1) {
    int x = (t >= off) ? sd[t - off] : 0;
    __syncthreads();
    sd[t] += x;
    __syncthreads();
  }
  if (t < 503) boff[t] = sd[t] - v;
}

// ---------------- scan step 3: rowptr + per-node cursor (= rowptr copy)
__global__ void __launch_bounds__(256) k_scan3(const int* __restrict__ counts, const int* __restrict__ boff,
                                               int* __restrict__ rowptr, int* __restrict__ cursor) {
  __shared__ int sd[256];
  int t = threadIdx.x;
  int i = blockIdx.x * 256 + t;
  int v = counts[i];
  sd[t] = v;
  __syncthreads();
  for (int off = 1; off < 256; off <<= 1) {
    int x = (t >= off) ? sd[t - off] : 0;
    __syncthreads();
    sd[t] += x;
    __syncthreads();
  }
  int excl = sd[t] - v + boff[blockIdx.x];
  rowptr[i] = excl;
  cursor[i] = excl;
  if (i == NNODE - 1) rowptr[NNODE] = excl + v;
}

// ---------------- XCD-range-exclusive scatter: group x (bid&7) commits only dst in its 1/8
// node range, so every pk cache line is written by one XCD only -> full L2 write merging.
__global__ void __launch_bounds__(256) k_scatter(const int* __restrict__ srcA,
                                                 const int* __restrict__ dstA,
                                                 const float* __restrict__ eattr,
                                                 int* __restrict__ cursor,
                                                 int2* __restrict__ pk) {
  int bid = blockIdx.x;
  int x = bid & 7;                  // XCD-group tag
  int j = bid >> 3;                 // block-within-group: 0..1005 (1006*2048 == NEDGE)
  int lo = x * (NNODE / 8);
  int hi = lo + (NNODE / 8);
  int e0 = j * 2048 + threadIdx.x;
#pragma unroll
  for (int k = 0; k < 8; ++k) {
    int e = e0 + k * 256;
    int d = dstA[e];
    if (d >= lo && d < hi) {
      int pos = atomicAdd(&cursor[d], 1);
      pk[pos] = make_int2(srcA[e], __float_as_int(eattr[e]));
    }
  }
}

// ---------------- layer kernel A: aggregate + t@w1+b1, BN1 stats; BN2(prev) affine fused
__global__ void __launch_bounds__(256) k_layerA(const float* __restrict__ hbuf,
                                                const int* __restrict__ rowptr,
                                                const int2* __restrict__ pk,
                                                const float* __restrict__ tab,
                                                const float* __restrict__ statsC,
                                                const float* __restrict__ bng,
                                                const float* __restrict__ bnb,
                                                const float* __restrict__ w1g,
                                                const float* __restrict__ b1g,
                                                const float* __restrict__ epsg,
                                                float* __restrict__ y1buf,
                                                float* __restrict__ statsA,
                                                int l, int relu) {
  __shared__ float w1s[HH * HH2];
  __shared__ float b1s[HH2];
  __shared__ float affs[HH], affsh[HH];
  __shared__ float tb[8][HH + 1];
  __shared__ float ps[HH2], pq[HH2];
  int t = threadIdx.x;
  const float* w1l = w1g + l * HH * HH2;
  for (int j = t; j < HH * HH2; j += 256) w1s[j] = w1l[j];
  if (t < HH2) { b1s[t] = b1g[l * HH2 + t]; ps[t] = 0.f; pq[t] = 0.f; }
  if (t < HH) {
    if (l == 0) { affs[t] = 1.f; affsh[t] = 0.f; }
    else {
      float sum = statsC[(l - 1) * 64 + t], sq = statsC[(l - 1) * 64 + 32 + t];
      float mean = sum / (float)NNODE;
      float var = fmaxf(sq / (float)NNODE - mean * mean, 0.f);
      float s = bng[(l - 1) * HH + t] * rsqrtf(var + BNEPS);
      affs[t] = s; affsh[t] = bnb[(l - 1) * HH + t] - mean * s;
    }
  }
  int g = t >> 5, c = t & 31;
  float epsv = 1.f + epsg[l];
  float lo = relu ? 0.f : -3.4e38f;
  const float angsc = (float)(TTAB - 1) / PI_F;
  float s0a = 0.f, s0q = 0.f, s1a = 0.f, s1q = 0.f;
  __syncthreads();
  float sc = affs[c], sh = affsh[c];
  int stride = gridDim.x * 8;
  int iters = (NNODE + stride - 1) / stride;
  int n = blockIdx.x * 8 + g;
  for (int it = 0; it < iters; ++it, n += stride) {
    bool val = n < NNODE;
    float tv = 0.f;
    if (val) {
      int p0 = rowptr[n], p1 = rowptr[n + 1];
      float hn = fmaxf(fmaf(hbuf[n * HH + c], sc, sh), lo);
      float acc = 0.f;
      int p = p0;
      for (; p + 4 <= p1; p += 4) {
        int2 q0 = pk[p], q1 = pk[p + 1], q2 = pk[p + 2], q3 = pk[p + 3];
        float h0 = hbuf[q0.x * HH + c];
        float h1 = hbuf[q1.x * HH + c];
        float h2 = hbuf[q2.x * HH + c];
        float h3 = hbuf[q3.x * HH + c];
        float u0 = __int_as_float(q0.y) * angsc; int i0 = min((int)u0, TTAB - 2); float f0 = u0 - (float)i0;
        float u1 = __int_as_float(q1.y) * angsc; int i1 = min((int)u1, TTAB - 2); float f1 = u1 - (float)i1;
        float u2 = __int_as_float(q2.y) * angsc; int i2 = min((int)u2, TTAB - 2); float f2 = u2 - (float)i2;
        float u3 = __int_as_float(q3.y) * angsc; int i3 = min((int)u3, TTAB - 2); float f3 = u3 - (float)i3;
        float t00 = tab[i0 * HH + c], t01 = tab[i0 * HH + HH + c];
        float t10 = tab[i1 * HH + c], t11 = tab[i1 * HH + HH + c];
        float t20 = tab[i2 * HH + c], t21 = tab[i2 * HH + HH + c];
        float t30 = tab[i3 * HH + c], t31 = tab[i3 * HH + HH + c];
        float e0 = fmaf(f0, t01 - t00, t00);
        float e1 = fmaf(f1, t11 - t10, t10);
        float e2 = fmaf(f2, t21 - t20, t20);
        float e3 = fmaf(f3, t31 - t30, t30);
        h0 = fmaxf(fmaf(h0, sc, sh), lo);
        h1 = fmaxf(fmaf(h1, sc, sh), lo);
        h2 = fmaxf(fmaf(h2, sc, sh), lo);
        h3 = fmaxf(fmaf(h3, sc, sh), lo);
        acc += fmaxf(h0 + e0, 0.f) + fmaxf(h1 + e1, 0.f) + fmaxf(h2 + e2, 0.f) + fmaxf(h3 + e3, 0.f);
      }
      for (; p < p1; ++p) {
        int2 q0 = pk[p];
        float h0 = fmaxf(fmaf(hbuf[q0.x * HH + c], sc, sh), lo);
        float u0 = __int_as_float(q0.y) * angsc; int i0 = min((int)u0, TTAB - 2); float f0 = u0 - (float)i0;
        float t00 = tab[i0 * HH + c], t01 = tab[i0 * HH + HH + c];
        acc += fmaxf(h0 + fmaf(f0, t01 - t00, t00), 0.f);
      }
      tv = fmaf(epsv, hn, acc);
    }
    tb[g][c] = tv;                      // intra-wave exchange (group g within wave g/2)
    __builtin_amdgcn_wave_barrier();
    if (val) {
      float y0 = b1s[c], y1 = b1s[HH + c];
#pragma unroll
      for (int k = 0; k < HH; ++k) {
        float tk = tb[g][k];
        y0 = fmaf(tk, w1s[k * HH2 + c], y0);
        y1 = fmaf(tk, w1s[k * HH2 + HH + c], y1);
      }
      y1buf[n * HH2 + c] = y0;
      y1buf[n * HH2 + HH + c] = y1;
      s0a += y0; s0q += y0 * y0; s1a += y1; s1q += y1 * y1;
    }
    __builtin_amdgcn_wave_barrier();
  }
  s0a += __shfl_xor(s0a, 32); s0q += __shfl_xor(s0q, 32);
  s1a += __shfl_xor(s1a, 32); s1q += __shfl_xor(s1q, 32);
  if ((t & 32) == 0) {
    atomicAdd(&ps[c], s0a); atomicAdd(&pq[c], s0q);
    atomicAdd(&ps[HH + c], s1a); atomicAdd(&pq[HH + c], s1q);
  }
  __syncthreads();
  if (t < HH2) {
    atomicAdd(&statsA[l * 128 + t], ps[t]);
    atomicAdd(&statsA[l * 128 + 64 + t], pq[t]);
  }
}

// ---------------- layer kernel C: BN1 solve fused; affine->relu->@w2+b2, BN2 stats
__global__ void __launch_bounds__(256) k_layerC(const float* __restrict__ y1buf,
                                                const float* __restrict__ statsA,
                                                const float* __restrict__ g1,
                                                const float* __restrict__ bb1,
                                                const float* __restrict__ w2g,
                                                const float* __restrict__ b2g,
                                                float* __restrict__ hbuf,
                                                float* __restrict__ statsC, int l) {
  __shared__ float w2s[HH2 * HH];
  __shared__ float b2s[HH];
  __shared__ float a1s[HH2], a1sh[HH2];
  __shared__ float ab[8][HH2 + 1];
  __shared__ float ps[HH], pq[HH];
  int t = threadIdx.x;
  const float* w2l = w2g + l * HH2 * HH;
  for (int j = t; j < HH2 * HH; j += 256) w2s[j] = w2l[j];
  if (t < HH) { b2s[t] = b2g[l * HH + t]; ps[t] = 0.f; pq[t] = 0.f; }
  if (t < HH2) {
    float sum = statsA[l * 128 + t], sq = statsA[l * 128 + 64 + t];
    float mean = sum / (float)NNODE;
    float var = fmaxf(sq / (float)NNODE - mean * mean, 0.f);
    float s = g1[l * HH2 + t] * rsqrtf(var + BNEPS);
    a1s[t] = s; a1sh[t] = bb1[l * HH2 + t] - mean * s;
  }
  int g = t >> 5, c = t & 31;
  float sa = 0.f, sq = 0.f;
  __syncthreads();
  int stride = gridDim.x * 8;
  int iters = (NNODE + stride - 1) / stride;
  int n = blockIdx.x * 8 + g;
  for (int it = 0; it < iters; ++it, n += stride) {
    bool val = n < NNODE;
    float a0 = 0.f, a1 = 0.f;
    if (val) {
      a0 = fmaf(y1buf[n * HH2 + c], a1s[c], a1sh[c]);
      a1 = fmaf(y1buf[n * HH2 + HH + c], a1s[HH + c], a1sh[HH + c]);
    }
    ab[g][c] = fmaxf(a0, 0.f);
    ab[g][HH + c] = fmaxf(a1, 0.f);
    __builtin_amdgcn_wave_barrier();
    if (val) {
      float z = b2s[c];
#pragma unroll
      for (int k = 0; k < HH2; ++k) z = fmaf(ab[g][k], w2s[k * HH + c], z);
      hbuf[n * HH + c] = z;
      sa += z; sq += z * z;
    }
    __builtin_amdgcn_wave_barrier();
  }
  sa += __shfl_xor(sa, 32); sq += __shfl_xor(sq, 32);
  if ((t & 32) == 0) { atomicAdd(&ps[c], sa); atomicAdd(&pq[c], sq); }
  __syncthreads();
  if (t < HH) {
    atomicAdd(&statsC[l * 64 + t], ps[t]);
    atomicAdd(&statsC[l * 64 + 32 + t], pq[t]);
  }
}

// ---------------- output: BN2(last) solve fused + LayerNorm + band-only writes
__global__ void __launch_bounds__(256) k_output(const float* __restrict__ hbuf,
                                                const float* __restrict__ statsC,
                                                const float* __restrict__ bng,
                                                const float* __restrict__ bnb,
                                                const float* __restrict__ lng,
                                                const float* __restrict__ lnb,
                                                float* __restrict__ out) {
  __shared__ float nrb[16 * 33];
  __shared__ float affs[HH], affsh[HH];
  int t = threadIdx.x;
  if (t < HH) {
    float sum = statsC[(NL - 1) * 64 + t], sq = statsC[(NL - 1) * 64 + 32 + t];
    float mean = sum / (float)NNODE;
    float var = fmaxf(sq / (float)NNODE - mean * mean, 0.f);
    float s = bng[(NL - 1) * HH + t] * rsqrtf(var + BNEPS);
    affs[t] = s; affsh[t] = bnb[(NL - 1) * HH + t] - mean * s;
  }
  __syncthreads();
  int gi = blockIdx.x;
  int g = gi >> 8, i = gi & 255;
  int jlo = (i - KBW > 0) ? i - KBW : 0;
  int jhi = (i + KBW < NNN - 1) ? i + KBW : NNN - 1;
  int cnt = jhi - jlo;  // valid count (excludes diagonal)
  int Ai = (i <= 8) ? i * (i - 1) / 2 : 28 + 8 * (i - 8);
  int Bi = (i <= 248) ? 8 * i : 2012 - (256 - i) * (255 - i) / 2;
  int nb = g * PGN + Ai + Bi;
  int r = t >> 5, c = t & 31;
  float sc = affs[c], sh = affsh[c];
  float lg = lng[c], lb = lnb[c];
  for (int rr = r; rr < cnt; rr += 8) {
    float v = fmaf(hbuf[(nb + rr) * HH + c], sc, sh);
    float s = v;
#pragma unroll
    for (int off = 16; off > 0; off >>= 1) s += __shfl_xor(s, off, 32);
    float mean = s * (1.f / 32.f);
    float d = v - mean;
    float q = d * d;
#pragma unroll
    for (int off = 16; off > 0; off >>= 1) q += __shfl_xor(q, off, 32);
    float var = q * (1.f / 32.f);
    nrb[rr * 33 + c] = d * rsqrtf(var + BNEPS) * lg + lb;
  }
  __syncthreads();
  int ch = t >> 3, k0 = t & 7;
  size_t base = (((size_t)g * HH + ch) * NNN + i) * NNN;
  for (int k = k0; k <= cnt; k += 8) {
    int j = jlo + k;
    if (j != i) {
      int rr = k - (j > i ? 1 : 0);
      out[base + j] = nrb[rr * 33 + ch];
    }
  }
}

extern "C" void kernel_launch(void* const* d_in, const int* in_sizes, int n_in,
                              void* d_out, int out_size, void* d_ws, size_t ws_size,
                              hipStream_t stream) {
  (void)in_sizes; (void)n_in;
  const float* x3d   = (const float*)d_in[0];
  const float* eattr = (const float*)d_in[1];
  const int*   eidx  = (const int*)d_in[2];
  const float* wlen = (const float*)d_in[5];
  const float* blen = (const float*)d_in[6];
  const float* wang = (const float*)d_in[7];
  const float* bang = (const float*)d_in[8];
  const float* w1g  = (const float*)d_in[9];
  const float* b1g  = (const float*)d_in[10];
  const float* g1   = (const float*)d_in[11];
  const float* bb1  = (const float*)d_in[12];
  const float* w2g  = (const float*)d_in[13];
  const float* b2g  = (const float*)d_in[14];
  const float* epsg = (const float*)d_in[15];
  const float* bng  = (const float*)d_in[16];
  const float* bnb  = (const float*)d_in[17];
  const float* lng  = (const float*)d_in[18];
  const float* lnb  = (const float*)d_in[19];
  float* out = (float*)d_out;

  char* ws = (char*)d_ws;
  size_t off = 0;
  auto alloc = [&](size_t bytes) {
    void* p = ws + off;
    off += (bytes + 255) & ~(size_t)255;
    return p;
  };
  int2*  pk         = (int2*)alloc((size_t)NEDGE * 8);
  int*   rowptr     = (int*)alloc((size_t)(NNODE + 1) * 4);
  int*   counts     = (int*)alloc((size_t)NNODE * 4);
  int*   cursor     = (int*)alloc((size_t)NNODE * 4);
  float* hbuf       = (float*)alloc((size_t)NNODE * HH * 4);
  float* y1buf      = (float*)alloc((size_t)NNODE * HH2 * 4);
  float* tab        = (float*)alloc((size_t)TTAB * HH * 4);
  float* statsA     = (float*)alloc(NL * 128 * 4);
  float* statsC     = (float*)alloc(NL * 64 * 4);
  int*   bsum       = (int*)alloc(503 * 4);
  int*   boff       = (int*)alloc(503 * 4);

  if (off > ws_size) {
    hipMemsetAsync(d_out, 0x7F, (size_t)out_size * 4, stream);
    return;
  }

  hipMemsetAsync(d_out, 0, (size_t)out_size * 4, stream);
  hipMemsetAsync(counts, 0, (size_t)NNODE * 4, stream);
  hipMemsetAsync(statsA, 0, NL * 128 * 4, stream);
  hipMemsetAsync(statsC, 0, NL * 64 * 4, stream);

  k_node_embed<<<NNODE * HH / 256, 256, 0, stream>>>(x3d, wlen, blen, hbuf);
  k_tab<<<TTAB * HH / 256, 256, 0, stream>>>(wang, bang, tab);
  k_hist<<<NEDGE / 256, 256, 0, stream>>>(eidx + NEDGE, counts);
  k_scan1<<<NNODE / 256, 256, 0, stream>>>(counts, bsum);
  k_scan2<<<1, 512, 0, stream>>>(bsum, boff);
  k_scan3<<<NNODE / 256, 256, 0, stream>>>(counts, boff, rowptr, cursor);
  k_scatter<<<8048, 256, 0, stream>>>(eidx, eidx + NEDGE, eattr, cursor, pk);

  for (int l = 0; l < NL; ++l) {
    k_layerA<<<2048, 256, 0, stream>>>(hbuf, rowptr, pk, tab, statsC, bng, bnb,
                                       w1g, b1g, epsg, y1buf, statsA, l, l >= 1 ? 1 : 0);
    k_layerC<<<2048, 256, 0, stream>>>(y1buf, statsA, g1, bb1, w2g, b2g, hbuf, statsC, l);
  }

  k_output<<<NNN * 32, 256, 0, stream>>>(hbuf, statsC, bng, bnb, lng, lnb, out);
}

// Round 8
// 1124.082 us; speedup vs baseline: 1.4325x; 1.0974x over previous
//
#include <hip/hip_runtime.h>
#include <hip/hip_bf16.h>

using bf16 = __hip_bfloat16;

#define HH 32
#define HH2 64
#define NRBF_ 20
#define NL 5
#define NNN 256
#define KBW 8
#define PGN 4024
#define TTAB 4096
constexpr int NNODE = 128768;
constexpr int NEDGE = 2060288;
constexpr float BNEPS = 1e-5f;
constexpr float PI_F = 3.14159265358979323846f;

// ---------------- node RBF embed -> f32 h
__global__ void __launch_bounds__(256) k_node_embed(const float* __restrict__ x3d,
                                                    const float* __restrict__ wlen,
                                                    const float* __restrict__ blen,
                                                    float* __restrict__ hbuf) {
  __shared__ float wl[NRBF_ * HH];
  __shared__ float bl[HH];
  int t = threadIdx.x;
  for (int j = t; j < NRBF_ * HH; j += 256) wl[j] = wlen[j];
  if (t < HH) bl[t] = blen[t];
  __syncthreads();
  int idx = blockIdx.x * 256 + t;
  int n = idx >> 5, c = idx & 31;
  float x = x3d[n];
  float acc = bl[c];
#pragma unroll
  for (int k = 0; k < NRBF_; ++k) {
    float d = x - 0.1f * (float)k;
    acc = fmaf(__expf(-10.f * d * d), wl[k * HH + c], acc);
  }
  hbuf[idx] = acc;
}

// ---------------- build ea nearest-neighbor table (4096 rows)
__global__ void __launch_bounds__(256) k_tab(const float* __restrict__ wang,
                                             const float* __restrict__ bang,
                                             float* __restrict__ tab) {
  __shared__ float wa[NRBF_ * HH];
  __shared__ float ba[HH];
  int t = threadIdx.x;
  for (int j = t; j < NRBF_ * HH; j += 256) wa[j] = wang[j];
  if (t < HH) ba[t] = bang[t];
  __syncthreads();
  int idx = blockIdx.x * 256 + t;
  int row = idx >> 5, c = idx & 31;
  float ang = (float)row * (PI_F / (float)(TTAB - 1));
  const float step = PI_F / 19.f;
  float acc = ba[c];
#pragma unroll
  for (int k = 0; k < NRBF_; ++k) {
    float d = ang - step * (float)k;
    acc = fmaf(__expf(-10.f * d * d), wa[k * HH + c], acc);
  }
  tab[row * HH + c] = acc;
}

// ---------------- histogram of dst
__global__ void __launch_bounds__(256) k_hist(const int* __restrict__ dst, int* __restrict__ counts) {
  int e = blockIdx.x * 256 + threadIdx.x;
  atomicAdd(&counts[dst[e]], 1);
}

// ---------------- scan step 1
__global__ void __launch_bounds__(256) k_scan1(const int* __restrict__ counts, int* __restrict__ bsum) {
  __shared__ int sd[256];
  int t = threadIdx.x;
  sd[t] = counts[blockIdx.x * 256 + t];
  __syncthreads();
  for (int s = 128; s > 0; s >>= 1) { if (t < s) sd[t] += sd[t + s]; __syncthreads(); }
  if (t == 0) bsum[blockIdx.x] = sd[0];
}

// ---------------- scan step 2
__global__ void __launch_bounds__(512) k_scan2(const int* __restrict__ bsum, int* __restrict__ boff) {
  __shared__ int sd[512];
  int t = threadIdx.x;
  int v = (t < 503) ? bsum[t] : 0;
  sd[t] = v;
  __syncthreads();
  for (int off = 1; off < 512; off <<= 1) {
    int x = (t >= off) ? sd[t - off] : 0;
    __syncthreads();
    sd[t] += x;
    __syncthreads();
  }
  if (t < 503) boff[t] = sd[t] - v;
}

// ---------------- scan step 3: rowptr + per-node cursor
__global__ void __launch_bounds__(256) k_scan3(const int* __restrict__ counts, const int* __restrict__ boff,
                                               int* __restrict__ rowptr, int* __restrict__ cursor) {
  __shared__ int sd[256];
  int t = threadIdx.x;
  int i = blockIdx.x * 256 + t;
  int v = counts[i];
  sd[t] = v;
  __syncthreads();
  for (int off = 1; off < 256; off <<= 1) {
    int x = (t >= off) ? sd[t - off] : 0;
    __syncthreads();
    sd[t] += x;
    __syncthreads();
  }
  int excl = sd[t] - v + boff[blockIdx.x];
  rowptr[i] = excl;
  cursor[i] = excl;
  if (i == NNODE - 1) rowptr[NNODE] = excl + v;
}

// ---------------- XCD-range-exclusive scatter (one XCD owns each pk line)
__global__ void __launch_bounds__(256) k_scatter(const int* __restrict__ srcA,
                                                 const int* __restrict__ dstA,
                                                 const float* __restrict__ eattr,
                                                 int* __restrict__ cursor,
                                                 int2* __restrict__ pk) {
  int bid = blockIdx.x;
  int x = bid & 7;
  int j = bid >> 3;
  int lo = x * (NNODE / 8);
  int hi = lo + (NNODE / 8);
  int e0 = j * 2048 + threadIdx.x;
#pragma unroll
  for (int k = 0; k < 8; ++k) {
    int e = e0 + k * 256;
    int d = dstA[e];
    if (d >= lo && d < hi) {
      int pos = atomicAdd(&cursor[d], 1);
      pk[pos] = make_int2(srcA[e], __float_as_int(eattr[e]));
    }
  }
}

// ---------------- layer kernel A: aggregate + t@w1+b1, BN1 stats; BN2(prev) affine fused
__global__ void __launch_bounds__(256) k_layerA(const float* __restrict__ hbuf,
                                                const int* __restrict__ rowptr,
                                                const int2* __restrict__ pk,
                                                const float* __restrict__ tab,
                                                const float* __restrict__ statsC,
                                                const float* __restrict__ bng,
                                                const float* __restrict__ bnb,
                                                const float* __restrict__ w1g,
                                                const float* __restrict__ b1g,
                                                const float* __restrict__ epsg,
                                                float* __restrict__ y1buf,
                                                float* __restrict__ statsA,
                                                int l, int relu) {
  __shared__ float w1s[HH * HH2];
  __shared__ float b1s[HH2];
  __shared__ float affs[HH], affsh[HH];
  __shared__ float tb[8][HH + 1];
  __shared__ float ps[HH2], pq[HH2];
  int t = threadIdx.x;
  const float* w1l = w1g + l * HH * HH2;
  for (int j = t; j < HH * HH2; j += 256) w1s[j] = w1l[j];
  if (t < HH2) { b1s[t] = b1g[l * HH2 + t]; ps[t] = 0.f; pq[t] = 0.f; }
  if (t < HH) {
    if (l == 0) { affs[t] = 1.f; affsh[t] = 0.f; }
    else {
      float sum = statsC[(l - 1) * 64 + t], sq = statsC[(l - 1) * 64 + 32 + t];
      float mean = sum / (float)NNODE;
      float var = fmaxf(sq / (float)NNODE - mean * mean, 0.f);
      float s = bng[(l - 1) * HH + t] * rsqrtf(var + BNEPS);
      affs[t] = s; affsh[t] = bnb[(l - 1) * HH + t] - mean * s;
    }
  }
  int g = t >> 5, c = t & 31;
  float epsv = 1.f + epsg[l];
  float lo = relu ? 0.f : -3.4e38f;
  const float angsc = (float)(TTAB - 1) / PI_F;
  float s0a = 0.f, s0q = 0.f, s1a = 0.f, s1q = 0.f;
  __syncthreads();
  float sc = affs[c], sh = affsh[c];
  int stride = gridDim.x * 8;
  int iters = (NNODE + stride - 1) / stride;
  int n = blockIdx.x * 8 + g;
  for (int it = 0; it < iters; ++it, n += stride) {
    bool val = n < NNODE;
    float tv = 0.f;
    if (val) {
      int p0 = rowptr[n], p1 = rowptr[n + 1];
      float hn = fmaxf(fmaf(hbuf[n * HH + c], sc, sh), lo);
      float acc = 0.f;
      int p = p0;
      for (; p + 8 <= p1; p += 8) {
        int2 q0 = pk[p], q1 = pk[p + 1], q2 = pk[p + 2], q3 = pk[p + 3];
        int2 q4 = pk[p + 4], q5 = pk[p + 5], q6 = pk[p + 6], q7 = pk[p + 7];
        float h0 = hbuf[q0.x * HH + c], h1 = hbuf[q1.x * HH + c];
        float h2 = hbuf[q2.x * HH + c], h3 = hbuf[q3.x * HH + c];
        float h4 = hbuf[q4.x * HH + c], h5 = hbuf[q5.x * HH + c];
        float h6 = hbuf[q6.x * HH + c], h7 = hbuf[q7.x * HH + c];
        int i0 = min((int)fmaf(__int_as_float(q0.y), angsc, 0.5f), TTAB - 1);
        int i1 = min((int)fmaf(__int_as_float(q1.y), angsc, 0.5f), TTAB - 1);
        int i2 = min((int)fmaf(__int_as_float(q2.y), angsc, 0.5f), TTAB - 1);
        int i3 = min((int)fmaf(__int_as_float(q3.y), angsc, 0.5f), TTAB - 1);
        int i4 = min((int)fmaf(__int_as_float(q4.y), angsc, 0.5f), TTAB - 1);
        int i5 = min((int)fmaf(__int_as_float(q5.y), angsc, 0.5f), TTAB - 1);
        int i6 = min((int)fmaf(__int_as_float(q6.y), angsc, 0.5f), TTAB - 1);
        int i7 = min((int)fmaf(__int_as_float(q7.y), angsc, 0.5f), TTAB - 1);
        float e0 = tab[i0 * HH + c], e1 = tab[i1 * HH + c];
        float e2 = tab[i2 * HH + c], e3 = tab[i3 * HH + c];
        float e4 = tab[i4 * HH + c], e5 = tab[i5 * HH + c];
        float e6 = tab[i6 * HH + c], e7 = tab[i7 * HH + c];
        h0 = fmaxf(fmaf(h0, sc, sh), lo); h1 = fmaxf(fmaf(h1, sc, sh), lo);
        h2 = fmaxf(fmaf(h2, sc, sh), lo); h3 = fmaxf(fmaf(h3, sc, sh), lo);
        h4 = fmaxf(fmaf(h4, sc, sh), lo); h5 = fmaxf(fmaf(h5, sc, sh), lo);
        h6 = fmaxf(fmaf(h6, sc, sh), lo); h7 = fmaxf(fmaf(h7, sc, sh), lo);
        acc += fmaxf(h0 + e0, 0.f) + fmaxf(h1 + e1, 0.f) + fmaxf(h2 + e2, 0.f) + fmaxf(h3 + e3, 0.f)
             + fmaxf(h4 + e4, 0.f) + fmaxf(h5 + e5, 0.f) + fmaxf(h6 + e6, 0.f) + fmaxf(h7 + e7, 0.f);
      }
      for (; p < p1; ++p) {
        int2 q0 = pk[p];
        float h0 = fmaxf(fmaf(hbuf[q0.x * HH + c], sc, sh), lo);
        int i0 = min((int)fmaf(__int_as_float(q0.y), angsc, 0.5f), TTAB - 1);
        acc += fmaxf(h0 + tab[i0 * HH + c], 0.f);
      }
      tv = fmaf(epsv, hn, acc);
    }
    tb[g][c] = tv;
    __builtin_amdgcn_wave_barrier();
    if (val) {
      float y0 = b1s[c], y1 = b1s[HH + c];
#pragma unroll
      for (int k = 0; k < HH; ++k) {
        float tk = tb[g][k];
        y0 = fmaf(tk, w1s[k * HH2 + c], y0);
        y1 = fmaf(tk, w1s[k * HH2 + HH + c], y1);
      }
      y1buf[n * HH2 + c] = y0;
      y1buf[n * HH2 + HH + c] = y1;
      s0a += y0; s0q += y0 * y0; s1a += y1; s1q += y1 * y1;
    }
    __builtin_amdgcn_wave_barrier();
  }
  s0a += __shfl_xor(s0a, 32); s0q += __shfl_xor(s0q, 32);
  s1a += __shfl_xor(s1a, 32); s1q += __shfl_xor(s1q, 32);
  if ((t & 32) == 0) {
    atomicAdd(&ps[c], s0a); atomicAdd(&pq[c], s0q);
    atomicAdd(&ps[HH + c], s1a); atomicAdd(&pq[HH + c], s1q);
  }
  __syncthreads();
  if (t < HH2) {
    atomicAdd(&statsA[l * 128 + t], ps[t]);
    atomicAdd(&statsA[l * 128 + 64 + t], pq[t]);
  }
}

// ---------------- layer kernel C: BN1 solve fused; affine->relu->@w2+b2, BN2 stats
__global__ void __launch_bounds__(256) k_layerC(const float* __restrict__ y1buf,
                                                const float* __restrict__ statsA,
                                                const float* __restrict__ g1,
                                                const float* __restrict__ bb1,
                                                const float* __restrict__ w2g,
                                                const float* __restrict__ b2g,
                                                float* __restrict__ hbuf,
                                                float* __restrict__ statsC, int l) {
  __shared__ float w2s[HH2 * HH];
  __shared__ float b2s[HH];
  __shared__ float a1s[HH2], a1sh[HH2];
  __shared__ float ab[8][HH2 + 1];
  __shared__ float ps[HH], pq[HH];
  int t = threadIdx.x;
  const float* w2l = w2g + l * HH2 * HH;
  for (int j = t; j < HH2 * HH; j += 256) w2s[j] = w2l[j];
  if (t < HH) { b2s[t] = b2g[l * HH + t]; ps[t] = 0.f; pq[t] = 0.f; }
  if (t < HH2) {
    float sum = statsA[l * 128 + t], sq = statsA[l * 128 + 64 + t];
    float mean = sum / (float)NNODE;
    float var = fmaxf(sq / (float)NNODE - mean * mean, 0.f);
    float s = g1[l * HH2 + t] * rsqrtf(var + BNEPS);
    a1s[t] = s; a1sh[t] = bb1[l * HH2 + t] - mean * s;
  }
  int g = t >> 5, c = t & 31;
  float sa = 0.f, sq = 0.f;
  __syncthreads();
  int stride = gridDim.x * 8;
  int iters = (NNODE + stride - 1) / stride;
  int n = blockIdx.x * 8 + g;
  for (int it = 0; it < iters; ++it, n += stride) {
    bool val = n < NNODE;
    float a0 = 0.f, a1 = 0.f;
    if (val) {
      a0 = fmaf(y1buf[n * HH2 + c], a1s[c], a1sh[c]);
      a1 = fmaf(y1buf[n * HH2 + HH + c], a1s[HH + c], a1sh[HH + c]);
    }
    ab[g][c] = fmaxf(a0, 0.f);
    ab[g][HH + c] = fmaxf(a1, 0.f);
    __builtin_amdgcn_wave_barrier();
    if (val) {
      float z = b2s[c];
#pragma unroll
      for (int k = 0; k < HH2; ++k) z = fmaf(ab[g][k], w2s[k * HH + c], z);
      hbuf[n * HH + c] = z;
      sa += z; sq += z * z;
    }
    __builtin_amdgcn_wave_barrier();
  }
  sa += __shfl_xor(sa, 32); sq += __shfl_xor(sq, 32);
  if ((t & 32) == 0) { atomicAdd(&ps[c], sa); atomicAdd(&pq[c], sq); }
  __syncthreads();
  if (t < HH) {
    atomicAdd(&statsC[l * 64 + t], ps[t]);
    atomicAdd(&statsC[l * 64 + 32 + t], pq[t]);
  }
}

// ---------------- output: BN2(last) solve fused + LayerNorm + FULL coalesced write (zeros incl.)
__global__ void __launch_bounds__(256) k_output(const float* __restrict__ hbuf,
                                                const float* __restrict__ statsC,
                                                const float* __restrict__ bng,
                                                const float* __restrict__ bnb,
                                                const float* __restrict__ lng,
                                                const float* __restrict__ lnb,
                                                float* __restrict__ out) {
  __shared__ float nrb[16 * 33];
  __shared__ float affs[HH], affsh[HH];
  int t = threadIdx.x;
  if (t < HH) {
    float sum = statsC[(NL - 1) * 64 + t], sq = statsC[(NL - 1) * 64 + 32 + t];
    float mean = sum / (float)NNODE;
    float var = fmaxf(sq / (float)NNODE - mean * mean, 0.f);
    float s = bng[(NL - 1) * HH + t] * rsqrtf(var + BNEPS);
    affs[t] = s; affsh[t] = bnb[(NL - 1) * HH + t] - mean * s;
  }
  __syncthreads();
  int gi = blockIdx.x;
  int g = gi >> 8, i = gi & 255;
  int jlo = (i - KBW > 0) ? i - KBW : 0;
  int jhi = (i + KBW < NNN - 1) ? i + KBW : NNN - 1;
  int cnt = jhi - jlo;  // valid count (excludes diagonal)
  int Ai = (i <= 8) ? i * (i - 1) / 2 : 28 + 8 * (i - 8);
  int Bi = (i <= 248) ? 8 * i : 2012 - (256 - i) * (255 - i) / 2;
  int nb = g * PGN + Ai + Bi;
  int r = t >> 5, c = t & 31;
  float sc = affs[c], sh = affsh[c];
  float lg = lng[c], lb = lnb[c];
  for (int rr = r; rr < cnt; rr += 8) {
    float v = fmaf(hbuf[(nb + rr) * HH + c], sc, sh);
    float s = v;
#pragma unroll
    for (int off = 16; off > 0; off >>= 1) s += __shfl_xor(s, off, 32);
    float mean = s * (1.f / 32.f);
    float d = v - mean;
    float q = d * d;
#pragma unroll
    for (int off = 16; off > 0; off >>= 1) q += __shfl_xor(q, off, 32);
    float var = q * (1.f / 32.f);
    nrb[rr * 33 + c] = d * rsqrtf(var + BNEPS) * lg + lb;
  }
  __syncthreads();
  int j = t;
  bool valid = (j >= jlo) & (j <= jhi) & (j != i);
  int rr = j - jlo - ((j > i) ? 1 : 0);
  rr = (rr < 0) ? 0 : ((rr > 15) ? 15 : rr);
  size_t ob = (((size_t)g * HH) * NNN + i) * NNN + j;
#pragma unroll
  for (int h = 0; h < HH; ++h) {
    float val = valid ? nrb[rr * 33 + h] : 0.f;
    __builtin_nontemporal_store(val, &out[ob + (size_t)h * NNN * NNN]);
  }
}

extern "C" void kernel_launch(void* const* d_in, const int* in_sizes, int n_in,
                              void* d_out, int out_size, void* d_ws, size_t ws_size,
                              hipStream_t stream) {
  (void)in_sizes; (void)n_in;
  const float* x3d   = (const float*)d_in[0];
  const float* eattr = (const float*)d_in[1];
  const int*   eidx  = (const int*)d_in[2];
  const float* wlen = (const float*)d_in[5];
  const float* blen = (const float*)d_in[6];
  const float* wang = (const float*)d_in[7];
  const float* bang = (const float*)d_in[8];
  const float* w1g  = (const float*)d_in[9];
  const float* b1g  = (const float*)d_in[10];
  const float* g1   = (const float*)d_in[11];
  const float* bb1  = (const float*)d_in[12];
  const float* w2g  = (const float*)d_in[13];
  const float* b2g  = (const float*)d_in[14];
  const float* epsg = (const float*)d_in[15];
  const float* bng  = (const float*)d_in[16];
  const float* bnb  = (const float*)d_in[17];
  const float* lng  = (const float*)d_in[18];
  const float* lnb  = (const float*)d_in[19];
  float* out = (float*)d_out;

  char* ws = (char*)d_ws;
  size_t off = 0;
  auto alloc = [&](size_t bytes) {
    void* p = ws + off;
    off += (bytes + 255) & ~(size_t)255;
    return p;
  };
  int2*  pk         = (int2*)alloc((size_t)NEDGE * 8);
  int*   rowptr     = (int*)alloc((size_t)(NNODE + 1) * 4);
  int*   counts     = (int*)alloc((size_t)NNODE * 4);
  int*   cursor     = (int*)alloc((size_t)NNODE * 4);
  float* hbuf       = (float*)alloc((size_t)NNODE * HH * 4);
  float* y1buf      = (float*)alloc((size_t)NNODE * HH2 * 4);
  float* tab        = (float*)alloc((size_t)TTAB * HH * 4);
  float* statsA     = (float*)alloc(NL * 128 * 4);
  float* statsC     = (float*)alloc(NL * 64 * 4);
  int*   bsum       = (int*)alloc(503 * 4);
  int*   boff       = (int*)alloc(503 * 4);

  if (off > ws_size) {
    hipMemsetAsync(d_out, 0x7F, (size_t)out_size * 4, stream);
    return;
  }

  hipMemsetAsync(counts, 0, (size_t)NNODE * 4, stream);
  hipMemsetAsync(statsA, 0, NL * 128 * 4, stream);
  hipMemsetAsync(statsC, 0, NL * 64 * 4, stream);

  k_node_embed<<<NNODE * HH / 256, 256, 0, stream>>>(x3d, wlen, blen, hbuf);
  k_tab<<<TTAB * HH / 256, 256, 0, stream>>>(wang, bang, tab);
  k_hist<<<NEDGE / 256, 256, 0, stream>>>(eidx + NEDGE, counts);
  k_scan1<<<NNODE / 256, 256, 0, stream>>>(counts, bsum);
  k_scan2<<<1, 512, 0, stream>>>(bsum, boff);
  k_scan3<<<NNODE / 256, 256, 0, stream>>>(counts, boff, rowptr, cursor);
  k_scatter<<<8048, 256, 0, stream>>>(eidx, eidx + NEDGE, eattr, cursor, pk);

  for (int l = 0; l < NL; ++l) {
    k_layerA<<<2048, 256, 0, stream>>>(hbuf, rowptr, pk, tab, statsC, bng, bnb,
                                       w1g, b1g, epsg, y1buf, statsA, l, l >= 1 ? 1 : 0);
    k_layerC<<<2048, 256, 0, stream>>>(y1buf, statsA, g1, bb1, w2g, b2g, hbuf, statsC, l);
  }

  k_output<<<NNN * 32, 256, 0, stream>>>(hbuf, statsC, bng, bnb, lng, lnb, out);
}